// Round 9
// baseline (880.529 us; speedup 1.0000x reference)
//
#include <hip/hip_runtime.h>
#include <hip/hip_cooperative_groups.h>
#include <float.h>

namespace cg = cooperative_groups;

#define NNODES 30000
#define NEDGES 480000
#define NFEATK 128
#define NH 16
#define NC 32
#define HC 512            // NH*NC
#define NCLASSES 10
#define NG 64
#define CAP 96            // padded per-node edge capacity (max deg ~45 for Poisson(16))
#define MBLK ((NNODES + 63) / 64)      // 469 row-tiles
#define VTILES (4 * MBLK)              // 1876 virtual gemm tiles (4 col-quadrants)
#define SMEM_HALVES 10240              // 20480 B: A(64x32) + 2x B(128x32) staging

using half2v = __attribute__((ext_vector_type(2))) _Float16;
using half4 = __attribute__((ext_vector_type(4))) _Float16;
using half8 = __attribute__((ext_vector_type(8))) _Float16;
using f32x4 = __attribute__((ext_vector_type(4))) float;

// ================= shared device-side phase bodies =================

__device__ __forceinline__ void prep_body(int gtid, int gstride,
                                          const float* Wl1, const float* Wr1,
                                          _Float16* Wlt1, _Float16* Wrt1,
                                          const float* Wl2, const float* Wr2,
                                          _Float16* Wlt2, _Float16* Wrt2,
                                          int* cnt, unsigned short* csr) {
    // W1 transposes (both l and r)
    for (int i = gtid; i < 2 * 512 * NFEATK; i += gstride) {
        int sel = i >= 512 * NFEATK;
        int idx = i - sel * 512 * NFEATK;
        const float* W = sel ? Wr1 : Wl1;
        _Float16* Wt = sel ? Wrt1 : Wlt1;
        int n = idx & 511, k = idx >> 9;
        Wt[n * NFEATK + k] = (_Float16)W[idx];
    }
    // W2 transposes
    for (int i = gtid; i < 2 * 512 * NC; i += gstride) {
        int sel = i >= 512 * NC;
        int idx = i - sel * 512 * NC;
        const float* W = sel ? Wr2 : Wl2;
        _Float16* Wt = sel ? Wrt2 : Wlt2;
        int n = idx & 511, k = idx >> 9;
        Wt[n * NC + k] = (_Float16)W[idx];
    }
    // bucket init: self-loop in slot 0, cnt = 1
    for (int i = gtid; i < NNODES; i += gstride) {
        cnt[i] = 1;
        csr[i * CAP] = (unsigned short)i;
    }
}

__device__ __forceinline__ void scatter_body(int gtid, int gstride,
                                             const int* src, const int* dst,
                                             int* cnt, unsigned short* csr) {
    for (int e = gtid; e < NEDGES; e += gstride) {
        int s = src[e], d = dst[e];
        int pos = atomicAdd(&cnt[d], 1);
        csr[d * CAP + pos] = (unsigned short)s;
    }
}

// merged-sel GEMM tile: one 64-row A-tile x one 128-col quadrant -> Yl AND Yr.
// KS=32 staging chunks; smem layout: A 64x32 | Bl 128x32 | Br 128x32 (20480 B).
template <int K, typename AT>
__device__ __forceinline__ void gemm_tile(int vt, const AT* A,
                                          const _Float16* Wlt, const _Float16* Wrt,
                                          const float* bl, const float* br,
                                          _Float16* Yl, _Float16* Yr, _Float16* smem) {
    constexpr int KS = 32;
    constexpr int KcS = KS / 8;          // 4
    constexpr int AH = 64 * KS;          // 2048 halves
    constexpr int BH = 128 * KS;         // 4096 halves
    _Float16* as = smem;
    _Float16* bsl = smem + AH;
    _Float16* bsr = smem + AH + BH;

    int tid = threadIdx.x;
    int nbase = (vt & 3) * 128;
    int mb = vt >> 2;

    int wave = tid >> 6, lane = tid & 63;
    int quad = lane >> 4, l16 = lane & 15;
    int am = l16 & (KcS - 1);

    f32x4 accl[8], accr[8];
    #pragma unroll
    for (int f = 0; f < 8; f++) {
        accl[f] = (f32x4){0.f, 0.f, 0.f, 0.f};
        accr[f] = (f32x4){0.f, 0.f, 0.f, 0.f};
    }

    #pragma unroll
    for (int ko = 0; ko < K / KS; ++ko) {
        __syncthreads();                 // protect LDS from previous chunk/tile use
        {   // stage A: 64*4 = 256 items, 1/thread
            int c = tid;
            int row = c >> 2, k8 = c & 3;
            int arow = mb * 64 + row; if (arow > NNODES - 1) arow = NNODES - 1;
            half8 v;
            if constexpr (sizeof(AT) == 4) {
                const float* ap = (const float*)&A[(size_t)arow * K + (ko * KcS + k8) * 8];
                float4 f0 = *(const float4*)ap;
                float4 f1 = *(const float4*)(ap + 4);
                v = half8{(_Float16)f0.x, (_Float16)f0.y, (_Float16)f0.z, (_Float16)f0.w,
                          (_Float16)f1.x, (_Float16)f1.y, (_Float16)f1.z, (_Float16)f1.w};
            } else {
                v = *(const half8*)&A[(size_t)arow * K + (ko * KcS + k8) * 8];
            }
            *(half8*)&as[(row * KcS + (k8 ^ (row & (KcS - 1)))) * 8] = v;
        }
        for (int c = tid; c < 2 * 128 * KcS; c += 256) {
            int sel = c >= 128 * KcS;
            int cc = c - sel * 128 * KcS;
            int row = cc >> 2, k8 = cc & 3;
            const _Float16* Bt = sel ? Wrt : Wlt;
            _Float16* bs = sel ? bsr : bsl;
            half8 v = *(const half8*)&Bt[(size_t)(nbase + row) * K + (ko * KcS + k8) * 8];
            *(half8*)&bs[(row * KcS + (k8 ^ (row & (KcS - 1)))) * 8] = v;
        }
        __syncthreads();

        int k8 = quad ^ am;
        half8 a = *(const half8*)&as[((wave * 16 + l16) * KcS + k8) * 8];
        #pragma unroll
        for (int f = 0; f < 8; f++) {
            half8 b = *(const half8*)&bsl[((f * 16 + l16) * KcS + k8) * 8];
            accl[f] = __builtin_amdgcn_mfma_f32_16x16x32_f16(a, b, accl[f], 0, 0, 0);
        }
        #pragma unroll
        for (int f = 0; f < 8; f++) {
            half8 b = *(const half8*)&bsr[((f * 16 + l16) * KcS + k8) * 8];
            accr[f] = __builtin_amdgcn_mfma_f32_16x16x32_f16(a, b, accr[f], 0, 0, 0);
        }
    }
    __syncthreads();

    _Float16* ys = smem;                 // reuse staging LDS (needs 64*136 <= fits? 8704 <= 10240 OK)
    int mtop = mb * 64;
    // ---- Yl ----
    #pragma unroll
    for (int f = 0; f < 8; f++) {
        float bv = bl[nbase + f * 16 + l16];
        #pragma unroll
        for (int r = 0; r < 4; r++)
            ys[(wave * 16 + quad * 4 + r) * 136 + f * 16 + l16] = (_Float16)(accl[f][r] + bv);
    }
    __syncthreads();
    for (int c = tid; c < 64 * 16; c += 256) {
        int r = c >> 4, cc = (c & 15) * 8;
        int grow = mtop + r;
        if (grow < NNODES)
            *(half8*)&Yl[(size_t)grow * HC + nbase + cc] = *(half8*)&ys[r * 136 + cc];
    }
    __syncthreads();
    // ---- Yr ----
    #pragma unroll
    for (int f = 0; f < 8; f++) {
        float bv = br[nbase + f * 16 + l16];
        #pragma unroll
        for (int r = 0; r < 4; r++)
            ys[(wave * 16 + quad * 4 + r) * 136 + f * 16 + l16] = (_Float16)(accr[f][r] + bv);
    }
    __syncthreads();
    for (int c = tid; c < 64 * 16; c += 256) {
        int r = c >> 4, cc = (c & 15) * 8;
        int grow = mtop + r;
        if (grow < NNODES)
            *(half8*)&Yr[(size_t)grow * HC + nbase + cc] = *(half8*)&ys[r * 136 + cc];
    }
}

// ---------------- GATv2 edge group: 4 nodes (one per wave), proven 74us shape ----------------
__device__ __forceinline__ half2v lrelu2(half2v e) {
    half2v s = e * half2v{(_Float16)0.2f, (_Float16)0.2f};
    return __builtin_elementwise_max(e, s);
}

#if __has_builtin(__builtin_amdgcn_fdot2)
#define FDOT2(a, b, c) __builtin_amdgcn_fdot2((a), (b), (c), false)
#else
__device__ __forceinline__ float fdot2_sw(half2v a, half2v b, float c) {
    half2v p = a * b;
    return c + (float)p.x + (float)p.y;
}
#define FDOT2(a, b, c) fdot2_sw((a), (b), (c))
#endif

template <typename OUT>
__device__ __forceinline__ void edge_group(int g, const _Float16* xlh, const _Float16* xrh,
                                           const float* att, const float* bvec,
                                           const int* cnt, const unsigned short* csr_src,
                                           OUT* hout) {
    int wv = threadIdx.x >> 6;           // wave in block -> node slot
    int t = threadIdx.x & 63;            // lane in wave
    int d = g * 4 + wv;                  // dst node (NNODES % 4 == 0)
    int col = t * 8;                     // head = t/4, 4 lanes per head

    half8 xrq = *(const half8*)&xrh[(unsigned)d * HC + col];
    half2v xr0 = {xrq[0], xrq[1]}, xr1 = {xrq[2], xrq[3]};
    half2v xr2 = {xrq[4], xrq[5]}, xr3 = {xrq[6], xrq[7]};
    float4 atta = *(const float4*)&att[col];
    float4 attb = *(const float4*)&att[col + 4];
    half2v at0 = {(_Float16)atta.x, (_Float16)atta.y};
    half2v at1 = {(_Float16)atta.z, (_Float16)atta.w};
    half2v at2 = {(_Float16)attb.x, (_Float16)attb.y};
    half2v at3 = {(_Float16)attb.z, (_Float16)attb.w};

    int beg = d * CAP, end = beg + cnt[d];

    float l = 0.f;
    float a[8];
    #pragma unroll
    for (int c = 0; c < 8; c++) a[c] = 0.f;

    for (int i = beg; i < end; i += 4) {
        int n = end - i;
        int s0 = csr_src[i];
        int s1 = csr_src[n > 1 ? i + 1 : i];
        int s2 = csr_src[n > 2 ? i + 2 : i];
        int s3 = csr_src[n > 3 ? i + 3 : i];
        half8 q0 = *(const half8*)&xlh[(unsigned)s0 * HC + col];
        half8 q1 = *(const half8*)&xlh[(unsigned)s1 * HC + col];
        half8 q2 = *(const half8*)&xlh[(unsigned)s2 * HC + col];
        half8 q3 = *(const half8*)&xlh[(unsigned)s3 * HC + col];

        float v0 = 0.f, v1 = 0.f, v2 = 0.f, v3 = 0.f;
        v0 = FDOT2(lrelu2(half2v{q0[0], q0[1]} + xr0), at0, v0);
        v0 = FDOT2(lrelu2(half2v{q0[2], q0[3]} + xr1), at1, v0);
        v0 = FDOT2(lrelu2(half2v{q0[4], q0[5]} + xr2), at2, v0);
        v0 = FDOT2(lrelu2(half2v{q0[6], q0[7]} + xr3), at3, v0);
        v1 = FDOT2(lrelu2(half2v{q1[0], q1[1]} + xr0), at0, v1);
        v1 = FDOT2(lrelu2(half2v{q1[2], q1[3]} + xr1), at1, v1);
        v1 = FDOT2(lrelu2(half2v{q1[4], q1[5]} + xr2), at2, v1);
        v1 = FDOT2(lrelu2(half2v{q1[6], q1[7]} + xr3), at3, v1);
        v2 = FDOT2(lrelu2(half2v{q2[0], q2[1]} + xr0), at0, v2);
        v2 = FDOT2(lrelu2(half2v{q2[2], q2[3]} + xr1), at1, v2);
        v2 = FDOT2(lrelu2(half2v{q2[4], q2[5]} + xr2), at2, v2);
        v2 = FDOT2(lrelu2(half2v{q2[6], q2[7]} + xr3), at3, v2);
        v3 = FDOT2(lrelu2(half2v{q3[0], q3[1]} + xr0), at0, v3);
        v3 = FDOT2(lrelu2(half2v{q3[2], q3[3]} + xr1), at1, v3);
        v3 = FDOT2(lrelu2(half2v{q3[4], q3[5]} + xr2), at2, v3);
        v3 = FDOT2(lrelu2(half2v{q3[6], q3[7]} + xr3), at3, v3);

        v0 += __shfl_xor(v0, 1); v1 += __shfl_xor(v1, 1);
        v2 += __shfl_xor(v2, 1); v3 += __shfl_xor(v3, 1);
        v0 += __shfl_xor(v0, 2); v1 += __shfl_xor(v1, 2);
        v2 += __shfl_xor(v2, 2); v3 += __shfl_xor(v3, 2);

        float p0 = __expf(v0);
        float p1 = (n > 1) ? __expf(v1) : 0.f;
        float p2 = (n > 2) ? __expf(v2) : 0.f;
        float p3 = (n > 3) ? __expf(v3) : 0.f;
        l += (p0 + p1) + (p2 + p3);

        #pragma unroll
        for (int c = 0; c < 8; c++) {
            a[c] += p0 * (float)q0[c];
            a[c] += p1 * (float)q1[c];
            a[c] += p2 * (float)q2[c];
            a[c] += p3 * (float)q3[c];
        }
    }

    float inv = 1.0f / l;
    #pragma unroll
    for (int c = 0; c < 8; c++) a[c] *= inv;

    #pragma unroll
    for (int off = 4; off < 64; off <<= 1) {
        #pragma unroll
        for (int c = 0; c < 8; c++) a[c] += __shfl_xor(a[c], off);
    }

    if (t < 4) {
        #pragma unroll
        for (int c = 0; c < 8; c++) {
            float r = a[c] * (1.0f / (float)NH) + bvec[t * 8 + c];
            r = (r > 0.f) ? r : 0.01f * r;
            hout[(size_t)d * NC + t * 8 + c] = (OUT)r;
        }
    }
}

// ---------------- pool + classify group (256 threads) ----------------
__device__ __forceinline__ void pool_group(int g, const float* h, const int* batch,
                                           const float* Wc, const float* bc,
                                           float* out, float* red) {
    int lo = 0, hi = NNODES;
    while (lo < hi) { int mid = (lo + hi) >> 1; if (batch[mid] < g) lo = mid + 1; else hi = mid; }
    int start = lo;
    hi = NNODES;
    while (lo < hi) { int mid = (lo + hi) >> 1; if (batch[mid] <= g) lo = mid + 1; else hi = mid; }
    int endn = lo;
    int cntg = endn - start;

    int tid = threadIdx.x;
    int c = tid & 31, nl = tid >> 5;              // 8 node-lanes x 32 channels
    float s = 0.f;
    for (int n = start + nl; n < endn; n += 8) s += h[n * NC + c];
    __syncthreads();                              // protect red reuse
    red[tid] = s;
    __syncthreads();
    if (tid < 32) {
        float t = 0.f;
        #pragma unroll
        for (int j = 0; j < 8; j++) t += red[j * 32 + tid];
        red[tid] = t / fmaxf((float)cntg, 1.0f);
    }
    __syncthreads();
    if (tid < NCLASSES) {
        float sum = bc[tid];
        #pragma unroll
        for (int cc = 0; cc < NC; cc++) sum += red[cc] * Wc[cc * NCLASSES + tid];
        out[g * NCLASSES + tid] = sum;
    }
}

// ================= cooperative mega-kernel =================
__launch_bounds__(256, 4)
__global__ void mega_kernel(const float* x,
                            const float* bl1, const float* br1, const float* att1, const float* b1,
                            const float* bl2, const float* br2, const float* att2, const float* b2,
                            const float* Wc, const float* bc,
                            const int* batch, float* out,
                            const int* src, const int* dst,
                            const float* Wl1, const float* Wr1, const float* Wl2, const float* Wr2,
                            _Float16* xlh, _Float16* xrh, _Float16* h1, float* h2,
                            _Float16* Wlt1, _Float16* Wrt1, _Float16* Wlt2, _Float16* Wrt2,
                            int* cnt, unsigned short* csr) {
    __shared__ __align__(16) _Float16 smem[SMEM_HALVES];
    cg::grid_group gg = cg::this_grid();
    int nb = gridDim.x, bid = blockIdx.x;
    int gtid = bid * 256 + threadIdx.x, gstride = nb * 256;

    // P0: W transposes + bucket init
    prep_body(gtid, gstride, Wl1, Wr1, Wlt1, Wrt1, Wl2, Wr2, Wlt2, Wrt2, cnt, csr);
    gg.sync();
    // P1: edge scatter
    scatter_body(gtid, gstride, src, dst, cnt, csr);
    gg.sync();
    // P2: gemm1 (A = x, f32)
    for (int vt = bid; vt < VTILES; vt += nb)
        gemm_tile<NFEATK, float>(vt, x, Wlt1, Wrt1, bl1, br1, xlh, xrh, smem);
    gg.sync();
    // P3: edge layer 1
    for (int g = bid; g < NNODES / 4; g += nb)
        edge_group<_Float16>(g, xlh, xrh, att1, b1, cnt, csr, h1);
    gg.sync();
    // P4: gemm2 (A = h1, f16)
    for (int vt = bid; vt < VTILES; vt += nb)
        gemm_tile<NC, _Float16>(vt, h1, Wlt2, Wrt2, bl2, br2, xlh, xrh, smem);
    gg.sync();
    // P5: edge layer 2
    for (int g = bid; g < NNODES / 4; g += nb)
        edge_group<float>(g, xlh, xrh, att2, b2, cnt, csr, h2);
    gg.sync();
    // P6: pool + classify
    for (int g = bid; g < NG; g += nb)
        pool_group(g, h2, batch, Wc, bc, out, (float*)smem);
}

// ================= fallback wrapper kernels (R6 structure) =================
__global__ void prep0_kernel(const float* Wl1, const float* Wr1,
                             _Float16* Wlt1, _Float16* Wrt1,
                             const float* Wl2, const float* Wr2,
                             _Float16* Wlt2, _Float16* Wrt2,
                             int* cnt, unsigned short* csr) {
    int gtid = blockIdx.x * blockDim.x + threadIdx.x;
    int gstride = gridDim.x * blockDim.x;
    prep_body(gtid, gstride, Wl1, Wr1, Wlt1, Wrt1, Wl2, Wr2, Wlt2, Wrt2, cnt, csr);
}

__global__ void scatter_kernel(const int* src, const int* dst,
                               int* cnt, unsigned short* csr) {
    int e = blockIdx.x * blockDim.x + threadIdx.x;
    if (e >= NEDGES) return;
    int s = src[e], d = dst[e];
    int pos = atomicAdd(&cnt[d], 1);
    csr[d * CAP + pos] = (unsigned short)s;
}

template <int K, typename AT>
__launch_bounds__(256)
__global__ void dual_gemm_kernel(const AT* A, const _Float16* Wlt, const _Float16* Wrt,
                                 const float* bl, const float* br,
                                 _Float16* Yl, _Float16* Yr) {
    __shared__ __align__(16) _Float16 smem[SMEM_HALVES];
    gemm_tile<K, AT>((blockIdx.y << 2) | blockIdx.x, A, Wlt, Wrt, bl, br, Yl, Yr, smem);
}

template <typename OUT>
__launch_bounds__(256)
__global__ void gat_edge_kernel(const _Float16* xlh, const _Float16* xrh,
                                const float* att, const float* bvec,
                                const int* cnt, const unsigned short* csr_src,
                                OUT* hout) {
    edge_group<OUT>(blockIdx.x, xlh, xrh, att, bvec, cnt, csr_src, hout);
}

__launch_bounds__(256)
__global__ void pool_classify_kernel(const float* h, const int* batch,
                                     const float* Wc, const float* bc, float* out) {
    __shared__ float red[256];
    pool_group(blockIdx.x, h, batch, Wc, bc, out, red);
}

// ================= launch =================

extern "C" void kernel_launch(void* const* d_in, const int* in_sizes, int n_in,
                              void* d_out, int out_size, void* d_ws, size_t ws_size,
                              hipStream_t stream) {
    const float* x    = (const float*)d_in[0];
    const float* Wl1  = (const float*)d_in[1];
    const float* bl1  = (const float*)d_in[2];
    const float* Wr1  = (const float*)d_in[3];
    const float* br1  = (const float*)d_in[4];
    const float* att1 = (const float*)d_in[5];
    const float* b1   = (const float*)d_in[6];
    const float* Wl2  = (const float*)d_in[7];
    const float* bl2  = (const float*)d_in[8];
    const float* Wr2  = (const float*)d_in[9];
    const float* br2  = (const float*)d_in[10];
    const float* att2 = (const float*)d_in[11];
    const float* b2   = (const float*)d_in[12];
    const float* Wc   = (const float*)d_in[13];
    const float* bc   = (const float*)d_in[14];
    const int* ei     = (const int*)d_in[15];
    const int* batch  = (const int*)d_in[16];
    float* out = (float*)d_out;

    const int* srcp = ei;
    const int* dstp = ei + NEDGES;

    char* ws = (char*)d_ws;
    size_t off = 0;
    auto alloc = [&](size_t bytes) -> void* {
        void* p = ws + off;
        off += (bytes + 255) & ~(size_t)255;
        return p;
    };
    _Float16* xlh  = (_Float16*)alloc(sizeof(_Float16) * (size_t)NNODES * HC);
    _Float16* xrh  = (_Float16*)alloc(sizeof(_Float16) * (size_t)NNODES * HC);
    _Float16* h1   = (_Float16*)alloc(sizeof(_Float16) * (size_t)NNODES * NC);
    float* h2      = (float*)alloc(sizeof(float) * (size_t)NNODES * NC);
    _Float16* Wlt1 = (_Float16*)alloc(sizeof(_Float16) * 512 * NFEATK);
    _Float16* Wrt1 = (_Float16*)alloc(sizeof(_Float16) * 512 * NFEATK);
    _Float16* Wlt2 = (_Float16*)alloc(sizeof(_Float16) * 512 * NC);
    _Float16* Wrt2 = (_Float16*)alloc(sizeof(_Float16) * 512 * NC);
    int*   cnt     = (int*)alloc(sizeof(int) * NNODES);
    unsigned short* csr = (unsigned short*)alloc(sizeof(unsigned short) * (size_t)NNODES * CAP);

    // cooperative grid sizing: co-resident blocks per CU x 256 CUs, capped
    int mbpc = 0;
    hipError_t qerr = hipOccupancyMaxActiveBlocksPerMultiprocessor(&mbpc, mega_kernel, 256, 0);
    int grid = (qerr == hipSuccess && mbpc >= 1) ? mbpc * 256 : 768;
    if (grid > 1024) grid = 1024;

    void* args[] = {
        (void*)&x,
        (void*)&bl1, (void*)&br1, (void*)&att1, (void*)&b1,
        (void*)&bl2, (void*)&br2, (void*)&att2, (void*)&b2,
        (void*)&Wc, (void*)&bc,
        (void*)&batch, (void*)&out,
        (void*)&srcp, (void*)&dstp,
        (void*)&Wl1, (void*)&Wr1, (void*)&Wl2, (void*)&Wr2,
        (void*)&xlh, (void*)&xrh, (void*)&h1, (void*)&h2,
        (void*)&Wlt1, (void*)&Wrt1, (void*)&Wlt2, (void*)&Wrt2,
        (void*)&cnt, (void*)&csr
    };

    hipError_t err = hipLaunchCooperativeKernel(mega_kernel, dim3(grid), dim3(256),
                                                args, 0, stream);
    if (err != hipSuccess) {
        (void)hipGetLastError();   // clear sticky error, fall back to multi-dispatch
        prep0_kernel<<<256, 256, 0, stream>>>(Wl1, Wr1, Wlt1, Wrt1,
                                              Wl2, Wr2, Wlt2, Wrt2, cnt, csr);
        scatter_kernel<<<(NEDGES + 255) / 256, 256, 0, stream>>>(srcp, dstp, cnt, csr);
        dual_gemm_kernel<NFEATK, float><<<dim3(4, MBLK), 256, 0, stream>>>(x, Wlt1, Wrt1, bl1, br1, xlh, xrh);
        gat_edge_kernel<_Float16><<<NNODES / 4, 256, 0, stream>>>(xlh, xrh, att1, b1, cnt, csr, h1);
        dual_gemm_kernel<NC, _Float16><<<dim3(4, MBLK), 256, 0, stream>>>(h1, Wlt2, Wrt2, bl2, br2, xlh, xrh);
        gat_edge_kernel<float><<<NNODES / 4, 256, 0, stream>>>(xlh, xrh, att2, b2, cnt, csr, h2);
        pool_classify_kernel<<<NG, 256, 0, stream>>>(h2, batch, Wc, bc, out);
    }
}

// Round 11
// 337.804 us; speedup vs baseline: 2.6066x; 2.6066x over previous
//
#include <hip/hip_runtime.h>
#include <float.h>

#define NNODES 30000
#define NEDGES 480000
#define NFEATK 128
#define NH 16
#define NC 32
#define HC 512            // NH*NC
#define NCLASSES 10
#define NG 64
#define CAP 96            // padded per-node edge capacity (max deg ~45 for Poisson(16))
#define MBLK ((NNODES + 63) / 64)      // 469 row-tiles
#define SCATB 512                      // scatter blocks inside fat1

using half2v = __attribute__((ext_vector_type(2))) _Float16;
using half4 = __attribute__((ext_vector_type(4))) _Float16;
using half8 = __attribute__((ext_vector_type(8))) _Float16;
using f32x4 = __attribute__((ext_vector_type(4))) float;

// ---------------- prep: W transposes only (cnt zeroed by memset; self-loops in scatter) ----------------
__global__ void prep_w_kernel(const float* __restrict__ Wl1, const float* __restrict__ Wr1,
                              _Float16* __restrict__ Wlt1, _Float16* __restrict__ Wrt1,
                              const float* __restrict__ Wl2, const float* __restrict__ Wr2,
                              _Float16* __restrict__ Wlt2, _Float16* __restrict__ Wrt2) {
    int gtid = blockIdx.x * blockDim.x + threadIdx.x;
    int gstride = gridDim.x * blockDim.x;
    for (int i = gtid; i < 2 * 512 * NFEATK; i += gstride) {
        int sel = i >= 512 * NFEATK;
        int idx = i - sel * 512 * NFEATK;
        const float* W = sel ? Wr1 : Wl1;
        _Float16* Wt = sel ? Wrt1 : Wlt1;
        int n = idx & 511, k = idx >> 9;
        Wt[n * NFEATK + k] = (_Float16)W[idx];
    }
    for (int i = gtid; i < 2 * 512 * NC; i += gstride) {
        int sel = i >= 512 * NC;
        int idx = i - sel * 512 * NC;
        const float* W = sel ? Wr2 : Wl2;
        _Float16* Wt = sel ? Wrt2 : Wlt2;
        int n = idx & 511, k = idx >> 9;
        Wt[n * NC + k] = (_Float16)W[idx];
    }
}

// ---------------- merged-sel GEMM body (R7-proven, KS=64 staging) ----------------
template <int K, typename AT>
__device__ __forceinline__ void gemm_body(int nbase, int mb, const AT* __restrict__ A,
                                          const _Float16* __restrict__ Wlt, const _Float16* __restrict__ Wrt,
                                          const float* __restrict__ bl, const float* __restrict__ br,
                                          _Float16* __restrict__ Yl, _Float16* __restrict__ Yr,
                                          _Float16* smem) {
    constexpr int KS = (K > 64) ? 64 : K;    // staged K-chunk
    constexpr int KcS = KS / 8;
    constexpr int AH = 64 * KS;
    constexpr int BH = 128 * KS;
    _Float16* as = smem;
    _Float16* bsl = smem + AH;
    _Float16* bsr = smem + AH + BH;

    int tid = threadIdx.x;
    int wave = tid >> 6, lane = tid & 63;
    int quad = lane >> 4, l16 = lane & 15;
    int am = l16 & (KcS - 1);

    f32x4 accl[8], accr[8];
    #pragma unroll
    for (int f = 0; f < 8; f++) {
        accl[f] = (f32x4){0.f, 0.f, 0.f, 0.f};
        accr[f] = (f32x4){0.f, 0.f, 0.f, 0.f};
    }

    #pragma unroll
    for (int ko = 0; ko < K / KS; ++ko) {
        if (ko) __syncthreads();             // protect LDS reuse across chunks
        for (int c = tid; c < 64 * KcS; c += 256) {
            int row = c / KcS, k8 = c % KcS;
            int arow = mb * 64 + row; if (arow > NNODES - 1) arow = NNODES - 1;
            half8 v;
            if constexpr (sizeof(AT) == 4) {
                const float* ap = (const float*)&A[(size_t)arow * K + (ko * KcS + k8) * 8];
                float4 f0 = *(const float4*)ap;
                float4 f1 = *(const float4*)(ap + 4);
                v = half8{(_Float16)f0.x, (_Float16)f0.y, (_Float16)f0.z, (_Float16)f0.w,
                          (_Float16)f1.x, (_Float16)f1.y, (_Float16)f1.z, (_Float16)f1.w};
            } else {
                v = *(const half8*)&A[(size_t)arow * K + (ko * KcS + k8) * 8];
            }
            *(half8*)&as[(row * KcS + (k8 ^ (row & (KcS - 1)))) * 8] = v;
        }
        for (int c = tid; c < 2 * 128 * KcS; c += 256) {
            int sel = c >= 128 * KcS;
            int cc = c - sel * 128 * KcS;
            int row = cc / KcS, k8 = cc % KcS;
            const _Float16* Bt = sel ? Wrt : Wlt;
            _Float16* bs = sel ? bsr : bsl;
            half8 v = *(const half8*)&Bt[(size_t)(nbase + row) * K + (ko * KcS + k8) * 8];
            *(half8*)&bs[(row * KcS + (k8 ^ (row & (KcS - 1)))) * 8] = v;
        }
        __syncthreads();

        #pragma unroll
        for (int kk = 0; kk < KcS; kk += 4) {
            int k8 = (kk + quad) ^ am;
            half8 a = *(const half8*)&as[((wave * 16 + l16) * KcS + k8) * 8];
            #pragma unroll
            for (int f = 0; f < 8; f++) {
                half8 b = *(const half8*)&bsl[((f * 16 + l16) * KcS + k8) * 8];
                accl[f] = __builtin_amdgcn_mfma_f32_16x16x32_f16(a, b, accl[f], 0, 0, 0);
            }
            #pragma unroll
            for (int f = 0; f < 8; f++) {
                half8 b = *(const half8*)&bsr[((f * 16 + l16) * KcS + k8) * 8];
                accr[f] = __builtin_amdgcn_mfma_f32_16x16x32_f16(a, b, accr[f], 0, 0, 0);
            }
        }
    }
    __syncthreads();

    _Float16* ys = smem;
    int mtop = mb * 64;
    // ---- Yl ----
    #pragma unroll
    for (int f = 0; f < 8; f++) {
        float bv = bl[nbase + f * 16 + l16];
        #pragma unroll
        for (int r = 0; r < 4; r++)
            ys[(wave * 16 + quad * 4 + r) * 136 + f * 16 + l16] = (_Float16)(accl[f][r] + bv);
    }
    __syncthreads();
    for (int c = tid; c < 64 * 16; c += 256) {
        int r = c >> 4, cc = (c & 15) * 8;
        int grow = mtop + r;
        if (grow < NNODES)
            *(half8*)&Yl[(size_t)grow * HC + nbase + cc] = *(half8*)&ys[r * 136 + cc];
    }
    __syncthreads();
    // ---- Yr ----
    #pragma unroll
    for (int f = 0; f < 8; f++) {
        float bv = br[nbase + f * 16 + l16];
        #pragma unroll
        for (int r = 0; r < 4; r++)
            ys[(wave * 16 + quad * 4 + r) * 136 + f * 16 + l16] = (_Float16)(accr[f][r] + bv);
    }
    __syncthreads();
    for (int c = tid; c < 64 * 16; c += 256) {
        int r = c >> 4, cc = (c & 15) * 8;
        int grow = mtop + r;
        if (grow < NNODES)
            *(half8*)&Yr[(size_t)grow * HC + nbase + cc] = *(half8*)&ys[r * 136 + cc];
    }
}

// ---------------- fat1: scatter (blocks [0,SCATB)) || gemm1 (rest) ----------------
// Scatter is data-independent of gemm1 -> overlap them in one dispatch.
__launch_bounds__(256)
__global__ void fat1_kernel(const float* __restrict__ x,
                            const _Float16* __restrict__ Wlt1, const _Float16* __restrict__ Wrt1,
                            const float* __restrict__ bl1, const float* __restrict__ br1,
                            _Float16* __restrict__ xlh, _Float16* __restrict__ xrh,
                            const int* __restrict__ src, const int* __restrict__ dst,
                            int* __restrict__ cnt, unsigned short* __restrict__ csr) {
    __shared__ __align__(16) _Float16 smem[64 * 64 + 2 * 128 * 64];
    if (blockIdx.x < SCATB) {
        // edge + self-loop scatter (cnt pre-zeroed by memset)
        int gtid = blockIdx.x * 256 + threadIdx.x;
        int gstride = SCATB * 256;
        for (int i = gtid; i < NEDGES + NNODES; i += gstride) {
            int s, d;
            if (i < NEDGES) { s = src[i]; d = dst[i]; }
            else            { d = i - NEDGES; s = d; }
            int pos = atomicAdd(&cnt[d], 1);
            csr[d * CAP + pos] = (unsigned short)s;
        }
        return;
    }
    int vt = blockIdx.x - SCATB;            // [0, 4*MBLK)
    gemm_body<NFEATK, float>((vt & 3) * 128, vt >> 2, x, Wlt1, Wrt1, bl1, br1, xlh, xrh, smem);
}

// ---------------- standalone dual GEMM (layer 2) ----------------
template <int K, typename AT>
__launch_bounds__(256)
__global__ void dual_gemm_kernel(const AT* __restrict__ A,
                                 const _Float16* __restrict__ Wlt, const _Float16* __restrict__ Wrt,
                                 const float* __restrict__ bl, const float* __restrict__ br,
                                 _Float16* __restrict__ Yl, _Float16* __restrict__ Yr) {
    constexpr int KS = (K > 64) ? 64 : K;
    constexpr int SM0 = 64 * KS + 2 * 128 * KS;
    constexpr int SM = (SM0 > 64 * 136) ? SM0 : 64 * 136;
    __shared__ __align__(16) _Float16 smem[SM];
    gemm_body<K, AT>(blockIdx.x * 128, blockIdx.y, A, Wlt, Wrt, bl, br, Yl, Yr, smem);
}

// ---------------- fused GATv2 edge stage: 4 nodes/block, 1 wave/node (proven 74us shape) ----------------
__device__ inline half2v lrelu2(half2v e) {
    half2v s = e * half2v{(_Float16)0.2f, (_Float16)0.2f};
    return __builtin_elementwise_max(e, s);
}

#if __has_builtin(__builtin_amdgcn_fdot2)
#define FDOT2(a, b, c) __builtin_amdgcn_fdot2((a), (b), (c), false)
#else
__device__ inline float fdot2_sw(half2v a, half2v b, float c) {
    half2v p = a * b;
    return c + (float)p.x + (float)p.y;
}
#define FDOT2(a, b, c) fdot2_sw((a), (b), (c))
#endif

template <typename OUT>
__launch_bounds__(256)
__global__ void gat_edge_kernel(const _Float16* __restrict__ xlh, const _Float16* __restrict__ xrh,
                                const float* __restrict__ att, const float* __restrict__ bvec,
                                const int* __restrict__ cnt, const unsigned short* __restrict__ csr_src,
                                OUT* __restrict__ hout) {
    int wv = threadIdx.x >> 6;           // wave in block -> node slot
    int t = threadIdx.x & 63;            // lane in wave
    int d = blockIdx.x * 4 + wv;         // dst node (NNODES % 4 == 0)
    int col = t * 8;                     // head = t/4, 4 lanes per head

    half8 xrq = *(const half8*)&xrh[(unsigned)d * HC + col];
    half2v xr0 = {xrq[0], xrq[1]}, xr1 = {xrq[2], xrq[3]};
    half2v xr2 = {xrq[4], xrq[5]}, xr3 = {xrq[6], xrq[7]};
    float4 atta = *(const float4*)&att[col];
    float4 attb = *(const float4*)&att[col + 4];
    half2v at0 = {(_Float16)atta.x, (_Float16)atta.y};
    half2v at1 = {(_Float16)atta.z, (_Float16)atta.w};
    half2v at2 = {(_Float16)attb.x, (_Float16)attb.y};
    half2v at3 = {(_Float16)attb.z, (_Float16)attb.w};

    int beg = d * CAP, end = beg + cnt[d];

    float l = 0.f;
    float a[8];
    #pragma unroll
    for (int c = 0; c < 8; c++) a[c] = 0.f;

    for (int i = beg; i < end; i += 4) {
        int n = end - i;
        int s0 = csr_src[i];
        int s1 = csr_src[n > 1 ? i + 1 : i];
        int s2 = csr_src[n > 2 ? i + 2 : i];
        int s3 = csr_src[n > 3 ? i + 3 : i];
        half8 q0 = *(const half8*)&xlh[(unsigned)s0 * HC + col];
        half8 q1 = *(const half8*)&xlh[(unsigned)s1 * HC + col];
        half8 q2 = *(const half8*)&xlh[(unsigned)s2 * HC + col];
        half8 q3 = *(const half8*)&xlh[(unsigned)s3 * HC + col];

        float v0 = 0.f, v1 = 0.f, v2 = 0.f, v3 = 0.f;
        v0 = FDOT2(lrelu2(half2v{q0[0], q0[1]} + xr0), at0, v0);
        v0 = FDOT2(lrelu2(half2v{q0[2], q0[3]} + xr1), at1, v0);
        v0 = FDOT2(lrelu2(half2v{q0[4], q0[5]} + xr2), at2, v0);
        v0 = FDOT2(lrelu2(half2v{q0[6], q0[7]} + xr3), at3, v0);
        v1 = FDOT2(lrelu2(half2v{q1[0], q1[1]} + xr0), at0, v1);
        v1 = FDOT2(lrelu2(half2v{q1[2], q1[3]} + xr1), at1, v1);
        v1 = FDOT2(lrelu2(half2v{q1[4], q1[5]} + xr2), at2, v1);
        v1 = FDOT2(lrelu2(half2v{q1[6], q1[7]} + xr3), at3, v1);
        v2 = FDOT2(lrelu2(half2v{q2[0], q2[1]} + xr0), at0, v2);
        v2 = FDOT2(lrelu2(half2v{q2[2], q2[3]} + xr1), at1, v2);
        v2 = FDOT2(lrelu2(half2v{q2[4], q2[5]} + xr2), at2, v2);
        v2 = FDOT2(lrelu2(half2v{q2[6], q2[7]} + xr3), at3, v2);
        v3 = FDOT2(lrelu2(half2v{q3[0], q3[1]} + xr0), at0, v3);
        v3 = FDOT2(lrelu2(half2v{q3[2], q3[3]} + xr1), at1, v3);
        v3 = FDOT2(lrelu2(half2v{q3[4], q3[5]} + xr2), at2, v3);
        v3 = FDOT2(lrelu2(half2v{q3[6], q3[7]} + xr3), at3, v3);

        v0 += __shfl_xor(v0, 1); v1 += __shfl_xor(v1, 1);
        v2 += __shfl_xor(v2, 1); v3 += __shfl_xor(v3, 1);
        v0 += __shfl_xor(v0, 2); v1 += __shfl_xor(v1, 2);
        v2 += __shfl_xor(v2, 2); v3 += __shfl_xor(v3, 2);

        float p0 = __expf(v0);
        float p1 = (n > 1) ? __expf(v1) : 0.f;
        float p2 = (n > 2) ? __expf(v2) : 0.f;
        float p3 = (n > 3) ? __expf(v3) : 0.f;
        l += (p0 + p1) + (p2 + p3);

        #pragma unroll
        for (int c = 0; c < 8; c++) {
            a[c] += p0 * (float)q0[c];
            a[c] += p1 * (float)q1[c];
            a[c] += p2 * (float)q2[c];
            a[c] += p3 * (float)q3[c];
        }
    }

    float inv = 1.0f / l;
    #pragma unroll
    for (int c = 0; c < 8; c++) a[c] *= inv;

    #pragma unroll
    for (int off = 4; off < 64; off <<= 1) {
        #pragma unroll
        for (int c = 0; c < 8; c++) a[c] += __shfl_xor(a[c], off);
    }

    if (t < 4) {
        #pragma unroll
        for (int c = 0; c < 8; c++) {
            float r = a[c] * (1.0f / (float)NH) + bvec[t * 8 + c];
            r = (r > 0.f) ? r : 0.01f * r;
            hout[(size_t)d * NC + t * 8 + c] = (OUT)r;
        }
    }
}

// ---------------- fused pool + classifier (R6-proven 1024-thread form) ----------------
__launch_bounds__(1024)
__global__ void pool_classify_kernel(const float* __restrict__ h, const int* __restrict__ batch,
                                     const float* __restrict__ Wc, const float* __restrict__ bc,
                                     float* __restrict__ out) {
    int g = blockIdx.x;
    int lo = 0, hi = NNODES;
    while (lo < hi) { int mid = (lo + hi) >> 1; if (batch[mid] < g) lo = mid + 1; else hi = mid; }
    int start = lo;
    hi = NNODES;
    while (lo < hi) { int mid = (lo + hi) >> 1; if (batch[mid] <= g) lo = mid + 1; else hi = mid; }
    int endn = lo;
    int cntg = endn - start;

    int tid = threadIdx.x;
    int c = tid & 31, nl = tid >> 5;              // 32 node-lanes x 32 channels
    float s = 0.f;
    for (int n = start + nl; n < endn; n += 32) s += h[n * NC + c];
    __shared__ float red[1024];
    red[tid] = s;
    __syncthreads();
    if (tid < 32) {
        float t = 0.f;
        #pragma unroll
        for (int j = 0; j < 32; j++) t += red[j * 32 + tid];
        red[tid] = t / fmaxf((float)cntg, 1.0f);
    }
    __syncthreads();
    if (tid < NCLASSES) {
        float sum = bc[tid];
        #pragma unroll
        for (int cc = 0; cc < NC; cc++) sum += red[cc] * Wc[cc * NCLASSES + tid];
        out[g * NCLASSES + tid] = sum;
    }
}

// ---------------- launch ----------------

extern "C" void kernel_launch(void* const* d_in, const int* in_sizes, int n_in,
                              void* d_out, int out_size, void* d_ws, size_t ws_size,
                              hipStream_t stream) {
    const float* x    = (const float*)d_in[0];
    const float* Wl1  = (const float*)d_in[1];
    const float* bl1  = (const float*)d_in[2];
    const float* Wr1  = (const float*)d_in[3];
    const float* br1  = (const float*)d_in[4];
    const float* att1 = (const float*)d_in[5];
    const float* b1   = (const float*)d_in[6];
    const float* Wl2  = (const float*)d_in[7];
    const float* bl2  = (const float*)d_in[8];
    const float* Wr2  = (const float*)d_in[9];
    const float* br2  = (const float*)d_in[10];
    const float* att2 = (const float*)d_in[11];
    const float* b2   = (const float*)d_in[12];
    const float* Wc   = (const float*)d_in[13];
    const float* bc   = (const float*)d_in[14];
    const int* ei     = (const int*)d_in[15];
    const int* batch  = (const int*)d_in[16];
    float* out = (float*)d_out;

    const int* srcp = ei;
    const int* dstp = ei + NEDGES;

    char* ws = (char*)d_ws;
    size_t off = 0;
    auto alloc = [&](size_t bytes) -> void* {
        void* p = ws + off;
        off += (bytes + 255) & ~(size_t)255;
        return p;
    };
    _Float16* xlh  = (_Float16*)alloc(sizeof(_Float16) * (size_t)NNODES * HC);
    _Float16* xrh  = (_Float16*)alloc(sizeof(_Float16) * (size_t)NNODES * HC);
    _Float16* h1   = (_Float16*)alloc(sizeof(_Float16) * (size_t)NNODES * NC);
    float* h2      = (float*)alloc(sizeof(float) * (size_t)NNODES * NC);
    _Float16* Wlt1 = (_Float16*)alloc(sizeof(_Float16) * 512 * NFEATK);
    _Float16* Wrt1 = (_Float16*)alloc(sizeof(_Float16) * 512 * NFEATK);
    _Float16* Wlt2 = (_Float16*)alloc(sizeof(_Float16) * 512 * NC);
    _Float16* Wrt2 = (_Float16*)alloc(sizeof(_Float16) * 512 * NC);
    int*   cnt     = (int*)alloc(sizeof(int) * NNODES);
    unsigned short* csr = (unsigned short*)alloc(sizeof(unsigned short) * (size_t)NNODES * CAP);

    // zero degree counters (async DMA, R8-proven safe under graph capture)
    hipMemsetAsync(cnt, 0, sizeof(int) * NNODES, stream);

    // W transposes (small, precedes gemm1)
    prep_w_kernel<<<128, 256, 0, stream>>>(Wl1, Wr1, Wlt1, Wrt1, Wl2, Wr2, Wlt2, Wrt2);

    // fat1: scatter (512 blocks) overlapped with gemm1 (1876 tiles)
    fat1_kernel<<<SCATB + 4 * MBLK, 256, 0, stream>>>(x, Wlt1, Wrt1, bl1, br1,
                                                      xlh, xrh, srcp, dstp, cnt, csr);

    // Layer 1 edge
    gat_edge_kernel<_Float16><<<NNODES / 4, 256, 0, stream>>>(xlh, xrh, att1, b1, cnt, csr, h1);

    // Layer 2
    dual_gemm_kernel<NC, _Float16><<<dim3(4, MBLK), 256, 0, stream>>>(h1, Wlt2, Wrt2, bl2, br2, xlh, xrh);
    gat_edge_kernel<float><<<NNODES / 4, 256, 0, stream>>>(xlh, xrh, att2, b2, cnt, csr, h2);

    // Pool + classify
    pool_classify_kernel<<<NG, 1024, 0, stream>>>(h2, batch, Wc, bc, out);
}

// Round 12
// 317.978 us; speedup vs baseline: 2.7692x; 1.0624x over previous
//
#include <hip/hip_runtime.h>
#include <float.h>

#define NNODES 30000
#define NEDGES 480000
#define NFEATK 128
#define NH 16
#define NC 32
#define HC 512            // NH*NC
#define NCLASSES 10
#define NG 64
#define CAP 96            // padded per-node edge capacity (max deg ~45 for Poisson(16))
#define MBLK ((NNODES + 63) / 64)      // 469 row-tiles

using half2v = __attribute__((ext_vector_type(2))) _Float16;
using half4 = __attribute__((ext_vector_type(4))) _Float16;
using half8 = __attribute__((ext_vector_type(8))) _Float16;
using f32x4 = __attribute__((ext_vector_type(4))) float;

// ---------------- prep: W transposes + bucket init (R6-proven) ----------------
__global__ void prep0_kernel(const float* __restrict__ Wl1, const float* __restrict__ Wr1,
                             _Float16* __restrict__ Wlt1, _Float16* __restrict__ Wrt1,
                             const float* __restrict__ Wl2, const float* __restrict__ Wr2,
                             _Float16* __restrict__ Wlt2, _Float16* __restrict__ Wrt2,
                             int* __restrict__ cnt, unsigned short* __restrict__ csr) {
    int gtid = blockIdx.x * blockDim.x + threadIdx.x;
    int gstride = gridDim.x * blockDim.x;
    // W1 transposes (both l and r)
    for (int i = gtid; i < 2 * 512 * NFEATK; i += gstride) {
        int sel = i >= 512 * NFEATK;
        int idx = i - sel * 512 * NFEATK;
        const float* W = sel ? Wr1 : Wl1;
        _Float16* Wt = sel ? Wrt1 : Wlt1;
        int n = idx & 511, k = idx >> 9;
        Wt[n * NFEATK + k] = (_Float16)W[idx];
    }
    // W2 transposes
    for (int i = gtid; i < 2 * 512 * NC; i += gstride) {
        int sel = i >= 512 * NC;
        int idx = i - sel * 512 * NC;
        const float* W = sel ? Wr2 : Wl2;
        _Float16* Wt = sel ? Wrt2 : Wlt2;
        int n = idx & 511, k = idx >> 9;
        Wt[n * NC + k] = (_Float16)W[idx];
    }
    // bucket init: self-loop in slot 0, cnt = 1
    for (int i = gtid; i < NNODES; i += gstride) {
        cnt[i] = 1;
        csr[i * CAP] = (unsigned short)i;
    }
}

// ---------------- bucket scatter: one atomic pass, u16 payload (R6-proven) ----------------
__global__ void scatter_kernel(const int* __restrict__ src, const int* __restrict__ dst,
                               int* __restrict__ cnt, unsigned short* __restrict__ csr) {
    int e = blockIdx.x * blockDim.x + threadIdx.x;
    if (e >= NEDGES) return;
    int s = src[e], d = dst[e];
    int pos = atomicAdd(&cnt[d], 1);
    csr[d * CAP + pos] = (unsigned short)s;
}

// ---------------- persistent B-resident GEMM ----------------
// Grid: dim3(8, PB). blockIdx.x: sel (l/r) x col-quadrant. Each block stages its
// 128-col B-slice ONCE (32 KB for K=128), then loops over M-tiles mb = gy, gy+PB, ...
// A-tile for the NEXT iteration is prefetched into registers before the MFMA
// cluster, so HBM latency hides under compute. Inner MFMA/swizzle/epilogue code
// is verbatim from the proven dual_gemm kernel (identical numerics).
template <int K, typename AT, int PB>
__launch_bounds__(256)
__global__ void persist_gemm_kernel(const AT* __restrict__ A,
                                    const _Float16* __restrict__ Wlt, const _Float16* __restrict__ Wrt,
                                    const float* __restrict__ bl, const float* __restrict__ br,
                                    _Float16* __restrict__ Yl, _Float16* __restrict__ Yr) {
    constexpr int Kc = K / 8;                          // half8 units per row
    constexpr int BHALF = 128 * K;                     // resident B halves
    constexpr int ASH = (64 * K > 64 * 136) ? 64 * K : 64 * 136;   // A region; aliases ys
    __shared__ __align__(16) _Float16 smem[BHALF + ASH];
    _Float16* bs = smem;
    _Float16* as = smem + BHALF;

    int tid = threadIdx.x;
    int sel = blockIdx.x >> 2;
    int nbase = (blockIdx.x & 3) * 128;
    const _Float16* Bt = sel ? Wrt : Wlt;
    const float* bias = sel ? br : bl;
    _Float16* Y = sel ? Yr : Yl;

    int wave = tid >> 6, lane = tid & 63;
    int quad = lane >> 4, l16 = lane & 15;
    int am = l16 & (Kc - 1);

    // stage B once — stays resident for all M-tiles of this block
    for (int c = tid; c < 128 * Kc; c += 256) {
        int row = c / Kc, k8 = c % Kc;
        half8 v = *(const half8*)&Bt[(size_t)(nbase + row) * K + k8 * 8];
        *(half8*)&bs[(row * Kc + (k8 ^ (row & (Kc - 1)))) * 8] = v;
    }

    constexpr int AJ = (64 * Kc) / 256;                // A half8-items per thread
    float4 fregs[2 * AJ];                              // used when AT == float
    half8  hregs[AJ];                                  // used when AT == _Float16

    auto load_a = [&](int mb) {
        #pragma unroll
        for (int j = 0; j < AJ; j++) {
            int c = tid + j * 256;
            int row = c / Kc, k8 = c % Kc;
            int arow = mb * 64 + row; if (arow > NNODES - 1) arow = NNODES - 1;
            if constexpr (sizeof(AT) == 4) {
                const float* ap = (const float*)&A[(size_t)arow * K + k8 * 8];
                fregs[2 * j]     = *(const float4*)ap;
                fregs[2 * j + 1] = *(const float4*)(ap + 4);
            } else {
                hregs[j] = *(const half8*)&A[(size_t)arow * K + k8 * 8];
            }
        }
    };
    auto write_a = [&]() {
        #pragma unroll
        for (int j = 0; j < AJ; j++) {
            int c = tid + j * 256;
            int row = c / Kc, k8 = c % Kc;
            half8 v;
            if constexpr (sizeof(AT) == 4) {
                float4 f0 = fregs[2 * j], f1 = fregs[2 * j + 1];
                v = half8{(_Float16)f0.x, (_Float16)f0.y, (_Float16)f0.z, (_Float16)f0.w,
                          (_Float16)f1.x, (_Float16)f1.y, (_Float16)f1.z, (_Float16)f1.w};
            } else {
                v = hregs[j];
            }
            *(half8*)&as[(row * Kc + (k8 ^ (row & (Kc - 1)))) * 8] = v;
        }
    };

    int mb = blockIdx.y;
    load_a(mb);
    while (mb < MBLK) {
        __syncthreads();                   // prior ys reads done; B visible on first iter
        write_a();
        __syncthreads();
        int nxt = mb + PB;
        if (nxt < MBLK) load_a(nxt);       // prefetch next A under the MFMA cluster

        f32x4 acc[8];
        #pragma unroll
        for (int f = 0; f < 8; f++) acc[f] = (f32x4){0.f, 0.f, 0.f, 0.f};
        #pragma unroll
        for (int kk = 0; kk < Kc; kk += 4) {
            int k8 = (kk + quad) ^ am;
            half8 a = *(const half8*)&as[((wave * 16 + l16) * Kc + k8) * 8];
            #pragma unroll
            for (int f = 0; f < 8; f++) {
                half8 b = *(const half8*)&bs[((f * 16 + l16) * Kc + k8) * 8];
                acc[f] = __builtin_amdgcn_mfma_f32_16x16x32_f16(a, b, acc[f], 0, 0, 0);
            }
        }
        __syncthreads();                   // as reads done before ys-alias writes

        _Float16* ys = as;                 // epilogue reuses the A region
        #pragma unroll
        for (int f = 0; f < 8; f++) {
            float bv = bias[nbase + f * 16 + l16];
            #pragma unroll
            for (int r = 0; r < 4; r++)
                ys[(wave * 16 + quad * 4 + r) * 136 + f * 16 + l16] = (_Float16)(acc[f][r] + bv);
        }
        __syncthreads();
        int mtop = mb * 64;
        for (int c = tid; c < 64 * 16; c += 256) {
            int r = c >> 4, cc = (c & 15) * 8;
            int grow = mtop + r;
            if (grow < NNODES)
                *(half8*)&Y[(size_t)grow * HC + nbase + cc] = *(half8*)&ys[r * 136 + cc];
        }
        mb = nxt;
    }
}

// ---------------- fused GATv2 edge stage: 4 nodes/block, 1 wave/node (proven 74us shape) ----------------
__device__ inline half2v lrelu2(half2v e) {
    half2v s = e * half2v{(_Float16)0.2f, (_Float16)0.2f};
    return __builtin_elementwise_max(e, s);
}

#if __has_builtin(__builtin_amdgcn_fdot2)
#define FDOT2(a, b, c) __builtin_amdgcn_fdot2((a), (b), (c), false)
#else
__device__ inline float fdot2_sw(half2v a, half2v b, float c) {
    half2v p = a * b;
    return c + (float)p.x + (float)p.y;
}
#define FDOT2(a, b, c) fdot2_sw((a), (b), (c))
#endif

template <typename OUT>
__launch_bounds__(256)
__global__ void gat_edge_kernel(const _Float16* __restrict__ xlh, const _Float16* __restrict__ xrh,
                                const float* __restrict__ att, const float* __restrict__ bvec,
                                const int* __restrict__ cnt, const unsigned short* __restrict__ csr_src,
                                OUT* __restrict__ hout) {
    int wv = threadIdx.x >> 6;           // wave in block -> node slot
    int t = threadIdx.x & 63;            // lane in wave
    int d = blockIdx.x * 4 + wv;         // dst node (NNODES % 4 == 0)
    int col = t * 8;                     // head = t/4, 4 lanes per head

    half8 xrq = *(const half8*)&xrh[(unsigned)d * HC + col];
    half2v xr0 = {xrq[0], xrq[1]}, xr1 = {xrq[2], xrq[3]};
    half2v xr2 = {xrq[4], xrq[5]}, xr3 = {xrq[6], xrq[7]};
    float4 atta = *(const float4*)&att[col];
    float4 attb = *(const float4*)&att[col + 4];
    half2v at0 = {(_Float16)atta.x, (_Float16)atta.y};
    half2v at1 = {(_Float16)atta.z, (_Float16)atta.w};
    half2v at2 = {(_Float16)attb.x, (_Float16)attb.y};
    half2v at3 = {(_Float16)attb.z, (_Float16)attb.w};

    int beg = d * CAP, end = beg + cnt[d];

    float l = 0.f;
    float a[8];
    #pragma unroll
    for (int c = 0; c < 8; c++) a[c] = 0.f;

    for (int i = beg; i < end; i += 4) {
        int n = end - i;
        int s0 = csr_src[i];
        int s1 = csr_src[n > 1 ? i + 1 : i];
        int s2 = csr_src[n > 2 ? i + 2 : i];
        int s3 = csr_src[n > 3 ? i + 3 : i];
        half8 q0 = *(const half8*)&xlh[(unsigned)s0 * HC + col];
        half8 q1 = *(const half8*)&xlh[(unsigned)s1 * HC + col];
        half8 q2 = *(const half8*)&xlh[(unsigned)s2 * HC + col];
        half8 q3 = *(const half8*)&xlh[(unsigned)s3 * HC + col];

        float v0 = 0.f, v1 = 0.f, v2 = 0.f, v3 = 0.f;
        v0 = FDOT2(lrelu2(half2v{q0[0], q0[1]} + xr0), at0, v0);
        v0 = FDOT2(lrelu2(half2v{q0[2], q0[3]} + xr1), at1, v0);
        v0 = FDOT2(lrelu2(half2v{q0[4], q0[5]} + xr2), at2, v0);
        v0 = FDOT2(lrelu2(half2v{q0[6], q0[7]} + xr3), at3, v0);
        v1 = FDOT2(lrelu2(half2v{q1[0], q1[1]} + xr0), at0, v1);
        v1 = FDOT2(lrelu2(half2v{q1[2], q1[3]} + xr1), at1, v1);
        v1 = FDOT2(lrelu2(half2v{q1[4], q1[5]} + xr2), at2, v1);
        v1 = FDOT2(lrelu2(half2v{q1[6], q1[7]} + xr3), at3, v1);
        v2 = FDOT2(lrelu2(half2v{q2[0], q2[1]} + xr0), at0, v2);
        v2 = FDOT2(lrelu2(half2v{q2[2], q2[3]} + xr1), at1, v2);
        v2 = FDOT2(lrelu2(half2v{q2[4], q2[5]} + xr2), at2, v2);
        v2 = FDOT2(lrelu2(half2v{q2[6], q2[7]} + xr3), at3, v2);
        v3 = FDOT2(lrelu2(half2v{q3[0], q3[1]} + xr0), at0, v3);
        v3 = FDOT2(lrelu2(half2v{q3[2], q3[3]} + xr1), at1, v3);
        v3 = FDOT2(lrelu2(half2v{q3[4], q3[5]} + xr2), at2, v3);
        v3 = FDOT2(lrelu2(half2v{q3[6], q3[7]} + xr3), at3, v3);

        v0 += __shfl_xor(v0, 1); v1 += __shfl_xor(v1, 1);
        v2 += __shfl_xor(v2, 1); v3 += __shfl_xor(v3, 1);
        v0 += __shfl_xor(v0, 2); v1 += __shfl_xor(v1, 2);
        v2 += __shfl_xor(v2, 2); v3 += __shfl_xor(v3, 2);

        float p0 = __expf(v0);
        float p1 = (n > 1) ? __expf(v1) : 0.f;
        float p2 = (n > 2) ? __expf(v2) : 0.f;
        float p3 = (n > 3) ? __expf(v3) : 0.f;
        l += (p0 + p1) + (p2 + p3);

        #pragma unroll
        for (int c = 0; c < 8; c++) {
            a[c] += p0 * (float)q0[c];
            a[c] += p1 * (float)q1[c];
            a[c] += p2 * (float)q2[c];
            a[c] += p3 * (float)q3[c];
        }
    }

    float inv = 1.0f / l;
    #pragma unroll
    for (int c = 0; c < 8; c++) a[c] *= inv;

    #pragma unroll
    for (int off = 4; off < 64; off <<= 1) {
        #pragma unroll
        for (int c = 0; c < 8; c++) a[c] += __shfl_xor(a[c], off);
    }

    if (t < 4) {
        #pragma unroll
        for (int c = 0; c < 8; c++) {
            float r = a[c] * (1.0f / (float)NH) + bvec[t * 8 + c];
            r = (r > 0.f) ? r : 0.01f * r;
            hout[(size_t)d * NC + t * 8 + c] = (OUT)r;
        }
    }
}

// ---------------- fused pool + classifier (R6-proven 1024-thread form) ----------------
__launch_bounds__(1024)
__global__ void pool_classify_kernel(const float* __restrict__ h, const int* __restrict__ batch,
                                     const float* __restrict__ Wc, const float* __restrict__ bc,
                                     float* __restrict__ out) {
    int g = blockIdx.x;
    int lo = 0, hi = NNODES;
    while (lo < hi) { int mid = (lo + hi) >> 1; if (batch[mid] < g) lo = mid + 1; else hi = mid; }
    int start = lo;
    hi = NNODES;
    while (lo < hi) { int mid = (lo + hi) >> 1; if (batch[mid] <= g) lo = mid + 1; else hi = mid; }
    int endn = lo;
    int cntg = endn - start;

    int tid = threadIdx.x;
    int c = tid & 31, nl = tid >> 5;              // 32 node-lanes x 32 channels
    float s = 0.f;
    for (int n = start + nl; n < endn; n += 32) s += h[n * NC + c];
    __shared__ float red[1024];
    red[tid] = s;
    __syncthreads();
    if (tid < 32) {
        float t = 0.f;
        #pragma unroll
        for (int j = 0; j < 32; j++) t += red[j * 32 + tid];
        red[tid] = t / fmaxf((float)cntg, 1.0f);
    }
    __syncthreads();
    if (tid < NCLASSES) {
        float sum = bc[tid];
        #pragma unroll
        for (int cc = 0; cc < NC; cc++) sum += red[cc] * Wc[cc * NCLASSES + tid];
        out[g * NCLASSES + tid] = sum;
    }
}

// ---------------- launch ----------------

extern "C" void kernel_launch(void* const* d_in, const int* in_sizes, int n_in,
                              void* d_out, int out_size, void* d_ws, size_t ws_size,
                              hipStream_t stream) {
    const float* x    = (const float*)d_in[0];
    const float* Wl1  = (const float*)d_in[1];
    const float* bl1  = (const float*)d_in[2];
    const float* Wr1  = (const float*)d_in[3];
    const float* br1  = (const float*)d_in[4];
    const float* att1 = (const float*)d_in[5];
    const float* b1   = (const float*)d_in[6];
    const float* Wl2  = (const float*)d_in[7];
    const float* bl2  = (const float*)d_in[8];
    const float* Wr2  = (const float*)d_in[9];
    const float* br2  = (const float*)d_in[10];
    const float* att2 = (const float*)d_in[11];
    const float* b2   = (const float*)d_in[12];
    const float* Wc   = (const float*)d_in[13];
    const float* bc   = (const float*)d_in[14];
    const int* ei     = (const int*)d_in[15];
    const int* batch  = (const int*)d_in[16];
    float* out = (float*)d_out;

    const int* srcp = ei;
    const int* dstp = ei + NEDGES;

    char* ws = (char*)d_ws;
    size_t off = 0;
    auto alloc = [&](size_t bytes) -> void* {
        void* p = ws + off;
        off += (bytes + 255) & ~(size_t)255;
        return p;
    };
    _Float16* xlh  = (_Float16*)alloc(sizeof(_Float16) * (size_t)NNODES * HC);
    _Float16* xrh  = (_Float16*)alloc(sizeof(_Float16) * (size_t)NNODES * HC);
    _Float16* h1   = (_Float16*)alloc(sizeof(_Float16) * (size_t)NNODES * NC);
    float* h2      = (float*)alloc(sizeof(float) * (size_t)NNODES * NC);
    _Float16* Wlt1 = (_Float16*)alloc(sizeof(_Float16) * 512 * NFEATK);
    _Float16* Wrt1 = (_Float16*)alloc(sizeof(_Float16) * 512 * NFEATK);
    _Float16* Wlt2 = (_Float16*)alloc(sizeof(_Float16) * 512 * NC);
    _Float16* Wrt2 = (_Float16*)alloc(sizeof(_Float16) * 512 * NC);
    int*   cnt     = (int*)alloc(sizeof(int) * NNODES);
    unsigned short* csr = (unsigned short*)alloc(sizeof(unsigned short) * (size_t)NNODES * CAP);

    // prep: W transposes + bucket init
    prep0_kernel<<<128, 256, 0, stream>>>(Wl1, Wr1, Wlt1, Wrt1, Wl2, Wr2, Wlt2, Wrt2, cnt, csr);
    // bucket scatter (one atomic pass)
    scatter_kernel<<<(NEDGES + 255) / 256, 256, 0, stream>>>(srcp, dstp, cnt, csr);

    // Layer 1 (A = x, f32, converted in-register during staging)
    persist_gemm_kernel<NFEATK, float, 96><<<dim3(8, 96), 256, 0, stream>>>(
        x, Wlt1, Wrt1, bl1, br1, xlh, xrh);
    gat_edge_kernel<_Float16><<<NNODES / 4, 256, 0, stream>>>(xlh, xrh, att1, b1, cnt, csr, h1);

    // Layer 2 (A = h1, f16)
    persist_gemm_kernel<NC, _Float16, 96><<<dim3(8, 96), 256, 0, stream>>>(
        h1, Wlt2, Wrt2, bl2, br2, xlh, xrh);
    gat_edge_kernel<float><<<NNODES / 4, 256, 0, stream>>>(xlh, xrh, att2, b2, cnt, csr, h2);

    // Pool + classify
    pool_classify_kernel<<<NG, 1024, 0, stream>>>(h2, batch, Wc, bc, out);
}